// Round 3
// baseline (282.483 us; speedup 1.0000x reference)
//
#include <hip/hip_runtime.h>
#include <hip/hip_bf16.h>
#include <cstdint>

// ---------------------------------------------------------------------------
// GemResNetBlock: two gauge-equivariant convs + Fourier ReLU + linear residual
// Round-16: round-15 counters showed zbuild ~85% stalled with occupancy 37%
// -> grid-limited (Z-chunking gives only ~3.7 blocks/CU), latency uncovered.
// Fix: split each (v,c) accumulator across 2 threads by q-halves (q0-4/q5-9)
// with ALL register indices compile-time constant (round-14's regression was
// dynamic acc[] indexing -> scratch, not the split itself):
//  * doubles resident waves (12.8KB LDS/block, ~7.3 blocks/CU)
//  * halves per-edge serial FMA depth (25 FMA instead of 50)
//  * C=32 wave = exactly 1 vertex -> no intra-wave degree divergence in L2
//  * static 5-shuffle exchange assembles the packed bf16 row at the end
// Keeps: edge_pack prepass (SRC + 48B REC, one sincos/edge), 1-iter-ahead
// software pipeline, zero-record clamp, LDS-staged line-coherent Z store.
#define NV     20000
#define NE     160000
#define IC1    16
#define OC     32
#define DIN    5
#define NSLOT  49
#define NOUT   160              // (o,i) = 32*5
// ---------------------------------------------------------------------------
struct SlotTables {
    int n;
    int b[64], f[64], i[64], j[64];
    float v[64];
};

constexpr SlotTables make_slots() {
    SlotTables T{};
    float K[19][5][5][5] = {};   // [basis][freq][row i][col j]
    int nb = 0;
    const int BL = 2;
    auto add = [&](int f, const float (*cb)[2], const float (*sb)[2],
                   int m, int n) {
        if (f > BL) return;
        int r0 = (m == 0) ? 0 : (2 * m - 1), nr = (m == 0) ? 1 : 2;
        int c0 = (n == 0) ? 0 : (2 * n - 1), nc = (n == 0) ? 1 : 2;
        for (int a = 0; a < nr; a++)
            for (int bb = 0; bb < nc; bb++) {
                if (f == 0) {
                    K[nb][0][r0 + a][c0 + bb] = cb[a][bb];
                } else {
                    K[nb][2 * f - 1][r0 + a][c0 + bb] = cb[a][bb];
                    K[nb][2 * f    ][r0 + a][c0 + bb] = sb[a][bb];
                }
            }
        nb++;
    };
    const float ONE[2][2]  = {{1, 0}, {0, 0}};
    const float I2[2][2]   = {{1, 0}, {0, 1}};
    const float E2[2][2]   = {{0, -1}, {1, 0}};
    const float S2[2][2]   = {{1, 0}, {0, -1}};
    const float ES2[2][2]  = {{0, 1}, {1, 0}};
    const float NS2[2][2]  = {{-1, 0}, {0, 1}};
    const float C10[2][2]  = {{1, 0}, {0, 0}};
    const float C01[2][2]  = {{0, 0}, {1, 0}};
    const float CM10[2][2] = {{-1, 0}, {0, 0}};
    const float R10[2][2]  = {{1, 0}, {0, 0}};
    const float R01[2][2]  = {{0, 1}, {0, 0}};
    const float RM10[2][2] = {{-1, 0}, {0, 0}};

    for (int m = 0; m <= 2; m++)
        for (int n = 0; n <= 2; n++) {
            if (m == 0 && n == 0) {
                add(0, ONE, ONE, 0, 0);
            } else if (n == 0) {
                add(m, C10, C01, m, 0);
                add(m, C01, CM10, m, 0);
            } else if (m == 0) {
                add(n, R10, R01, 0, n);
                add(n, R01, RM10, 0, n);
            } else {
                int d = m - n;
                int f = d >= 0 ? d : -d;
                float sg = d >= 0 ? 1.f : -1.f;
                const float sgE[2][2]  = {{0, -sg}, {sg, 0}};
                const float msgI[2][2] = {{-sg, 0}, {0, -sg}};
                add(f, I2, sgE, m, n);
                add(f, E2, msgI, m, n);
                add(m + n, S2, ES2, m, n);
                add(m + n, ES2, NS2, m, n);
            }
        }
    T.n = 0;
    for (int i = 0; i < 5; i++)
        for (int b = 0; b < nb; b++)
            for (int f = 0; f < 5; f++)
                for (int j = 0; j < 5; j++)
                    if (K[b][f][i][j] != 0.0f) {
                        T.b[T.n] = b; T.f[T.n] = f; T.i[T.n] = i;
                        T.j[T.n] = j; T.v[T.n] = K[b][f][i][j];
                        T.n++;
                    }
    return T;
}

constexpr SlotTables SL = make_slots();
static_assert(SL.n == NSLOT, "expect 49 kernel-basis nonzeros");

__device__ __forceinline__ uint32_t bf16_rne(float f) {
    uint32_t u = __float_as_uint(f);
    u += 0x7fffu + ((u >> 16) & 1u);
    return u >> 16;
}

typedef __attribute__((ext_vector_type(8))) short bf16x8;   // MFMA A/B frag
typedef __attribute__((ext_vector_type(4))) float f32x4;    // MFMA C/D frag

// ---------------- M build: M[k][n], k=(c*50+j*10+q), n=(o*5+i) -------------
template<int C>
__global__ __launch_bounds__(256) void build_M(const float* __restrict__ W,
                                               float* __restrict__ M) {
    int t = blockIdx.x * 256 + threadIdx.x;
    const int K = C * 50;
    if (t >= K * NOUT) return;
    int n = t % NOUT, k = t / NOUT;
    int o = n / 5, i = n % 5;
    int c = k / 50, r50 = k % 50;
    int j = r50 / 10, q = r50 % 10;
    int f = q >> 1, r = q & 1;
    float acc = 0.f;
    #pragma unroll
    for (int s = 0; s < NSLOT; s++) {
        if (SL.j[s] == j && SL.f[s] == f && SL.i[s] == i)
            acc += SL.v[s] * W[(size_t)((SL.b[s] * 2 + r) * 32 + o) * C + c];
    }
    M[(size_t)k * NOUT + n] = acc;
}

// Swizzle M into MFMA B-fragment order (bf16):
// Mf[((ck*10+nt)*64+lane)*4+a] packs B[k0][col],B[k0+1][col]
// with k0 = ck*32 + (lane>>4)*8 + 2a, col = nt*16 + (lane&15).
template<int K>
__global__ __launch_bounds__(256) void build_Mfrag(const float* __restrict__ M,
                                                   uint32_t* __restrict__ Mf) {
    int t = blockIdx.x * 256 + threadIdx.x;
    const int total = (K / 32) * 10 * 64 * 4;
    if (t >= total) return;
    int a = t & 3;
    int idx = t >> 2;
    int lane = idx & 63; idx >>= 6;
    int nt = idx % 10;
    int ck = idx / 10;
    int col = nt * 16 + (lane & 15);
    int k0 = ck * 32 + (lane >> 4) * 8 + 2 * a;
    uint32_t lo = bf16_rne(M[(size_t)k0 * NOUT + col]);
    uint32_t hi = bf16_rne(M[(size_t)(k0 + 1) * NOUT + col]);
    Mf[t] = lo | (hi << 16);
}

// ---------------- CSR build ------------------------------------------------
__global__ __launch_bounds__(256) void hist_k(const int* __restrict__ ei,
                                              int* __restrict__ counts) {
    int e = blockIdx.x * 256 + threadIdx.x;
    if (e < NE) atomicAdd(&counts[ei[e]], 1);   // ei[e] = dst
}

__global__ __launch_bounds__(1024) void scan_k(const int* __restrict__ counts,
                                               int* __restrict__ cursor) {
    __shared__ int part[1024];
    int t = threadIdx.x;
    int base = t * 20;
    int local[20];
    int s = 0;
    #pragma unroll
    for (int k = 0; k < 20; k++) {
        int idx = base + k;
        int c = (idx < NV) ? counts[idx] : 0;
        local[k] = c; s += c;
    }
    part[t] = s;
    __syncthreads();
    for (int off = 1; off < 1024; off <<= 1) {
        int add = (t >= off) ? part[t - off] : 0;
        __syncthreads();
        part[t] += add;
        __syncthreads();
    }
    int run = (t == 0) ? 0 : part[t - 1];
    #pragma unroll
    for (int k = 0; k < 20; k++) {
        int idx = base + k;
        if (idx < NV) { cursor[idx] = run; run += local[k]; }
    }
}

__global__ __launch_bounds__(256) void scatter_k(const int* __restrict__ ei,
                                                 int* __restrict__ cursor,
                                                 int* __restrict__ order) {
    int e = blockIdx.x * 256 + threadIdx.x;
    if (e >= NE) return;
    int pos = atomicAdd(&cursor[ei[e]], 1);
    order[pos] = e;
}

// ---------------- edge prepass: CSR-ordered edge records -------------------
// SRC[k] = src vertex of k-th CSR edge; REC[k] = {c1,s1,p0..p9} (3 float4).
// Slot k = NE holds a zero record (p = 0) used to clamp the zbuild pipeline.
__global__ __launch_bounds__(256) void edge_pack(const int* __restrict__ ei,
                                                 const float* __restrict__ pre,
                                                 const float* __restrict__ conn,
                                                 const int* __restrict__ order,
                                                 int* __restrict__ SRC,
                                                 float4* __restrict__ REC) {
    int k = blockIdx.x * 256 + threadIdx.x;
    if (k > NE) return;
    if (k == NE) {
        SRC[NE] = 0;
        REC[(size_t)NE * 3 + 0] = float4{0.f, 0.f, 0.f, 0.f};
        REC[(size_t)NE * 3 + 1] = float4{0.f, 0.f, 0.f, 0.f};
        REC[(size_t)NE * 3 + 2] = float4{0.f, 0.f, 0.f, 0.f};
        return;
    }
    int e = order[k];
    SRC[k] = ei[NE + e];
    float al = conn[e];
    float c1 = __cosf(al), s1 = __sinf(al);
    const float* pp = pre + (size_t)e * 10;
    REC[(size_t)k * 3 + 0] = float4{c1, s1, pp[0], pp[1]};
    REC[(size_t)k * 3 + 1] = float4{pp[2], pp[3], pp[4], pp[5]};
    REC[(size_t)k * 3 + 2] = float4{pp[6], pp[7], pp[8], pp[9]};
}

// ---------------- Z build v4: 2 threads per (v,c), q-split accumulator -----
// Thread t: pair = t>>1 = (v-v0)*C + c, h = t&1.  Lane h owns q-half
// {5h..5h+4}: acc[j*5+w] = sum_e xt[j]*p[5h+w].  Every register-array index
// is compile-time constant (ph[] picked via constant-index ternaries; the
// round-14 scratch trap was runtime acc[] indexing).  Edge loop software-
// pipelined one iteration ahead.  Final pack: 5 static __shfl_xor(.,1) give
// lane h=0 the q5 values; pair writes its 25-uint row into LDS, then the
// block does a linear line-coherent global writeout.
template<int C>
__global__ __launch_bounds__(256) void zbuild4(const float* __restrict__ xin,
                                               const int*   __restrict__ SRC,
                                               const float4* __restrict__ REC,
                                               const int* __restrict__ cursor,
                                               uint32_t* __restrict__ Z,
                                               int v0, int v1) {
    __shared__ uint32_t st[3200];        // 128 pairs x 25 uints = 12.8 KB
    int tid = threadIdx.x;
    int t = blockIdx.x * 256 + tid;
    int pair = t >> 1, h = t & 1;
    int npairs = (v1 - v0) * C;
    bool valid = pair < npairs;
    int c = pair % C;
    int v = v0 + (valid ? pair / C : 0);
    int beg = 0, end = 0;
    if (valid) { beg = (v == 0) ? 0 : cursor[v - 1]; end = cursor[v]; }

    float acc[25];
    #pragma unroll
    for (int z = 0; z < 25; z++) acc[z] = 0.f;

    int k = beg;
    if (k < end) {
        // prologue: edge k fully loaded, src of k+1 prefetched
        int kn = (k + 1 < end) ? k + 1 : NE;
        int sC = SRC[k];
        int sN = SRC[kn];
        const float4* rp = REC + (size_t)k * 3;
        float4 r0 = rp[0], r1 = rp[1], r2 = rp[2];
        const float* xb = xin + ((size_t)sC * C + c) * DIN;
        float x0 = xb[0], x1 = xb[1], x2 = xb[2], x3 = xb[3], x4 = xb[4];
        while (true) {
            bool more = (k + 1 < end);
            int kn2 = (k + 2 < end) ? k + 2 : NE;
            int sN2 = SRC[kn2];
            // issue next edge's loads (sN ready since last iteration)
            const float* xbn = xin + ((size_t)sN * C + c) * DIN;
            float y0 = xbn[0], y1 = xbn[1], y2 = xbn[2], y3 = xbn[3],
                  y4 = xbn[4];
            const float4* rpn = REC + (size_t)kn * 3;
            float4 n0 = rpn[0], n1 = rpn[1], n2 = rpn[2];
            // compute current edge
            float c1 = r0.x, s1 = r0.y;
            float c2 = c1 * c1 - s1 * s1, s2 = 2.f * c1 * s1;
            float xt[5];
            xt[0] = x0;
            xt[1] = c1 * x1 - s1 * x2;
            xt[2] = s1 * x1 + c1 * x2;
            xt[3] = c2 * x3 - s2 * x4;
            xt[4] = s2 * x3 + c2 * x4;
            // q-half select, constant component indices only
            float ph[5];
            ph[0] = h ? r1.w : r0.z;    // p5 : p0
            ph[1] = h ? r2.x : r0.w;    // p6 : p1
            ph[2] = h ? r2.y : r1.x;    // p7 : p2
            ph[3] = h ? r2.z : r1.y;    // p8 : p3
            ph[4] = h ? r2.w : r1.z;    // p9 : p4
            #pragma unroll
            for (int j = 0; j < 5; j++)
                #pragma unroll
                for (int w = 0; w < 5; w++)
                    acc[j * 5 + w] = fmaf(xt[j], ph[w], acc[j * 5 + w]);
            if (!more) break;
            k += 1;
            r0 = n0; r1 = n1; r2 = n2;
            x0 = y0; x1 = y1; x2 = y2; x3 = y3; x4 = y4;
            sN = sN2; kn = kn2;
        }
    }
    // assemble the 25-uint packed row for this pair.
    // uint u = j*5+w holds z=(j*10+2w, j*10+2w+1) i.e. q-pair (2w, 2w+1):
    //   w=0,1 -> q0..3 (h=0 local); w=2 -> q4 (h=0) + q5 (h=1, shfl);
    //   w=3,4 -> q6..9 (h=1 local)
    uint32_t* sb = st + (tid >> 1) * 25;
    #pragma unroll
    for (int j = 0; j < 5; j++) {
        float q5v = __shfl_xor(acc[j * 5 + 0], 1);   // h=1's p5-acc -> h=0
        if (h == 0) {
            sb[j * 5 + 0] = bf16_rne(acc[j * 5 + 0]) | (bf16_rne(acc[j * 5 + 1]) << 16);
            sb[j * 5 + 1] = bf16_rne(acc[j * 5 + 2]) | (bf16_rne(acc[j * 5 + 3]) << 16);
            sb[j * 5 + 2] = bf16_rne(acc[j * 5 + 4]) | (bf16_rne(q5v) << 16);
        } else {
            sb[j * 5 + 3] = bf16_rne(acc[j * 5 + 1]) | (bf16_rne(acc[j * 5 + 2]) << 16);
            sb[j * 5 + 4] = bf16_rne(acc[j * 5 + 3]) | (bf16_rne(acc[j * 5 + 4]) << 16);
        }
    }
    __syncthreads();
    // linear block writeout: each store inst covers contiguous cache lines
    size_t gbase = (size_t)blockIdx.x * 3200;
    int pbase = blockIdx.x * 128;
    for (int i = tid; i < 3200; i += 256)
        if (pbase + i / 25 < npairs) Z[gbase + i] = st[i];
}

// ---------------- MFMA GEMM: Y[v,n] = sum_k Z[v,k]*M[k,n] ------------------
// 4 waves/block, 64 rows/block, all 160 cols.  B-frags (identical for the 4
// waves) live in double-buffered LDS, filled by async DMA (global_load_lds,
// width 16): per chunk, stage chunk ck+1 into Bs[buf^1] BEFORE computing ck,
// prefetch A one chunk ahead in regs, one __syncthreads per chunk.
template<int K>
__global__ __launch_bounds__(256) void gemm_mfma(const uint32_t* __restrict__ Z,
                                                 const uint32_t* __restrict__ Mf,
                                                 float* __restrict__ Y,
                                                 int rows) {
    constexpr int NC = K / 32;
    __shared__ uint4 Bs[2][640];        // 2 x 10 KB
    int t = threadIdx.x;
    int lane = t & 63;
    int wave = t >> 6;
    int r0 = blockIdx.x * 64 + wave * 16;
    int mrow = lane & 15;
    int q = lane >> 4;
    int ra = r0 + mrow;
    if (ra >= rows) ra = rows - 1;          // clamp A loads; store masked
    const uint32_t* za = Z + (size_t)ra * (K / 2) + q * 4;
    const uint4* mfg = (const uint4*)Mf + lane;

    auto stage = [&](int ck, int nb) {
        const uint4* gp = mfg + (size_t)ck * 640;
        for (int i = wave; i < 10; i += 4)
            __builtin_amdgcn_global_load_lds(
                (const __attribute__((address_space(1))) void*)(gp + i * 64),
                (__attribute__((address_space(3))) void*)(&Bs[nb][i * 64]),
                16, 0, 0);
    };

    f32x4 acc[10];
    #pragma unroll
    for (int nt = 0; nt < 10; nt++) acc[nt] = {0.f, 0.f, 0.f, 0.f};

    stage(0, 0);
    bf16x8 af = *(const bf16x8*)za;         // A chunk 0 (overlaps DMA wait)
    __syncthreads();

    for (int ck = 0; ck < NC; ck++) {
        int buf = ck & 1;
        bf16x8 af_n = af;
        if (ck + 1 < NC) {
            stage(ck + 1, buf ^ 1);         // async DMA, consumed next iter
            af_n = *(const bf16x8*)(za + (ck + 1) * 16);
        }
        bf16x8 bf[10];
        #pragma unroll
        for (int nt = 0; nt < 10; nt++)
            bf[nt] = *(const bf16x8*)&Bs[buf][nt * 64 + lane];
        #pragma unroll
        for (int nt = 0; nt < 10; nt++)
            acc[nt] = __builtin_amdgcn_mfma_f32_16x16x32_bf16(af, bf[nt],
                                                              acc[nt], 0, 0, 0);
        af = af_n;
        __syncthreads();                    // drain DMA + protect Bs[buf]
    }
    // C/D layout: col = lane&15, row = q*4 + reg  [verified m89/m91]
    #pragma unroll
    for (int reg = 0; reg < 4; reg++) {
        int rr = r0 + q * 4 + reg;
        if (rr < rows) {
            float* yb = Y + (size_t)rr * NOUT + (lane & 15);
            #pragma unroll
            for (int nt = 0; nt < 10; nt++) yb[nt * 16] = acc[nt][reg];
        }
    }
}

// ---------------- Fourier ReLU + epilogues ---------------------------------
__device__ __forceinline__ void fourier_relu(float d0, float d1, float d2,
                                             float d3, float d4, float* out5) {
    float o0 = 0, o1 = 0, o2 = 0, o3 = 0, o4 = 0;
    #pragma unroll
    for (int k = 0; k < 7; k++) {
        float th = (float)k * (6.28318530717958647692f / 7.0f);
        float ck = __cosf(th), sk = __sinf(th);
        float c2k = ck * ck - sk * sk, s2k = 2.f * ck * sk;
        float sv = d0 + ck * d1 + sk * d2 + c2k * d3 + s2k * d4;
        sv = fmaxf(sv, 0.f);
        o0 += sv; o1 += sv * ck; o2 += sv * sk; o3 += sv * c2k; o4 += sv * s2k;
    }
    const float i7 = 1.0f / 7.0f;
    out5[0] = o0 * i7; out5[1] = o1 * (2.f * i7); out5[2] = o2 * (2.f * i7);
    out5[3] = o3 * (2.f * i7); out5[4] = o4 * (2.f * i7);
}

__global__ __launch_bounds__(256) void relu_mid(float* __restrict__ y,
                                                const float* __restrict__ b1) {
    int t = blockIdx.x * 256 + threadIdx.x;     // v*32 + ch
    if (t >= NV * 32) return;
    int ch = t & 31;
    float* yb = y + (size_t)t * 5;
    float r[5];
    fourier_relu(yb[0] + b1[ch], yb[1], yb[2], yb[3], yb[4], r);
    #pragma unroll
    for (int d = 0; d < 5; d++) yb[d] = r[d];
}

__global__ __launch_bounds__(256) void final_k(const float* __restrict__ y2,
                                               const float* __restrict__ x,
                                               const float* __restrict__ Wl,
                                               const float* __restrict__ bl,
                                               const float* __restrict__ b2,
                                               float* __restrict__ out) {
    int t = blockIdx.x * 256 + threadIdx.x;     // v*32 + o
    if (t >= NV * 32) return;
    int o = t & 31;
    int v = t >> 5;
    float r0 = 0, r1 = 0, r2 = 0, r3 = 0, r4 = 0;
    const float* xb = x + (size_t)v * (IC1 * DIN);
    const float* wl = Wl + o * IC1;
    #pragma unroll
    for (int c = 0; c < IC1; c++) {
        float w = wl[c];
        r0 = fmaf(w, xb[c*5+0], r0); r1 = fmaf(w, xb[c*5+1], r1);
        r2 = fmaf(w, xb[c*5+2], r2); r3 = fmaf(w, xb[c*5+3], r3);
        r4 = fmaf(w, xb[c*5+4], r4);
    }
    float blo = bl[o];
    const float* yb = y2 + (size_t)t * 5;
    float d0 = yb[0] + b2[o] + r0 + blo;
    float d1 = yb[1] + r1 + blo;
    float d2 = yb[2] + r2 + blo;
    float d3 = yb[3] + r3 + blo;
    float d4 = yb[4] + r4 + blo;
    float r[5];
    fourier_relu(d0, d1, d2, d3, d4, r);
    float* ob = out + (size_t)t * 5;
    #pragma unroll
    for (int d = 0; d < 5; d++) ob[d] = r[d];
}

extern "C" void kernel_launch(void* const* d_in, const int* in_sizes, int n_in,
                              void* d_out, int out_size, void* d_ws, size_t ws_size,
                              hipStream_t stream) {
    const float* x    = (const float*)d_in[0];
    const int*   ei   = (const int*)  d_in[1];
    const float* pre  = (const float*)d_in[2];
    const float* conn = (const float*)d_in[3];
    const float* W1   = (const float*)d_in[4];
    const float* b1   = (const float*)d_in[5];
    const float* W2   = (const float*)d_in[6];
    const float* b2   = (const float*)d_in[7];
    const float* Wl   = (const float*)d_in[8];
    const float* bl   = (const float*)d_in[9];
    float* out = (float*)d_out;

    const int K1 = IC1 * 50;   // 800
    const int K2 = OC  * 50;   // 1600

    // ws layout: y1 | y2 | M1 | M2 | Mf1 | Mf2 | csr | REC | SRC | Ztail
    const size_t Y_BYTES   = (size_t)NV * NOUT * sizeof(float);     // 12.8 MB
    const size_t M1_BYTES  = (size_t)K1 * NOUT * sizeof(float);     // 512 KB
    const size_t M2_BYTES  = (size_t)K2 * NOUT * sizeof(float);     // 1 MB
    const size_t MF1_BYTES = (size_t)(K1 / 32) * 10 * 64 * 16;      // 256 KB
    const size_t MF2_BYTES = (size_t)(K2 / 32) * 10 * 64 * 16;      // 512 KB
    const size_t CSR_BYTES = (size_t)(2 * NV + NE) * sizeof(int);   // 800 KB
    const size_t REC_BYTES = (size_t)(NE + 1) * 48;                 // 7.68 MB
    const size_t SRC_BYTES = (((size_t)(NE + 1) * 4 + 15) / 16) * 16;
    char* ws = (char*)d_ws;
    float* y1 = (float*)(ws);
    float* y2 = (float*)(ws + Y_BYTES);
    float* M1 = (float*)(ws + 2 * Y_BYTES);
    float* M2 = (float*)(ws + 2 * Y_BYTES + M1_BYTES);
    uint32_t* Mf1 = (uint32_t*)(ws + 2 * Y_BYTES + M1_BYTES + M2_BYTES);
    uint32_t* Mf2 = (uint32_t*)(ws + 2 * Y_BYTES + M1_BYTES + M2_BYTES + MF1_BYTES);
    int* counts = (int*)(ws + 2 * Y_BYTES + M1_BYTES + M2_BYTES + MF1_BYTES + MF2_BYTES);
    int* cursor = counts + NV;
    int* order  = cursor + NV;
    size_t csr_end = 2 * Y_BYTES + M1_BYTES + M2_BYTES + MF1_BYTES + MF2_BYTES
                   + CSR_BYTES;
    float4* REC = (float4*)(ws + csr_end);
    int*    SRC = (int*)(ws + csr_end + REC_BYTES);
    size_t fixed = csr_end + REC_BYTES + SRC_BYTES;

    // Z buffer (bf16): ws tail if it has room, else d_out (dead until final_k)
    size_t tail = (ws_size > fixed) ? (ws_size - fixed) : 0;
    uint32_t* zbuf;
    size_t zcap;
    if (tail >= Y_BYTES) { zbuf = (uint32_t*)(ws + fixed); zcap = tail; }
    else                 { zbuf = (uint32_t*)d_out;        zcap = Y_BYTES; }
    int chunk1 = (int)(zcap / ((size_t)K1 * 2)); if (chunk1 > NV) chunk1 = NV;
    int chunk2 = (int)(zcap / ((size_t)K2 * 2)); if (chunk2 > NV) chunk2 = NV;

    hipMemsetAsync(counts, 0, NV * sizeof(int), stream);

    build_M<IC1><<<(K1 * NOUT + 255) / 256, 256, 0, stream>>>(W1, M1);
    build_M<OC> <<<(K2 * NOUT + 255) / 256, 256, 0, stream>>>(W2, M2);
    build_Mfrag<K1><<<((K1 / 32) * 2560 + 255) / 256, 256, 0, stream>>>(M1, Mf1);
    build_Mfrag<K2><<<((K2 / 32) * 2560 + 255) / 256, 256, 0, stream>>>(M2, Mf2);

    hist_k   <<<(NE + 255) / 256, 256, 0, stream>>>(ei, counts);
    scan_k   <<<1, 1024, 0, stream>>>(counts, cursor);
    scatter_k<<<(NE + 255) / 256, 256, 0, stream>>>(ei, cursor, order);
    edge_pack<<<(NE + 256) / 256, 256, 0, stream>>>(ei, pre, conn, order,
                                                    SRC, REC);

    // layer 1
    for (int v0 = 0; v0 < NV; v0 += chunk1) {
        int v1 = v0 + chunk1; if (v1 > NV) v1 = NV;
        int rows = v1 - v0;
        zbuild4<IC1><<<((size_t)rows * IC1 * 2 + 255) / 256, 256, 0, stream>>>(
            x, SRC, REC, cursor, zbuf, v0, v1);
        gemm_mfma<K1><<<(rows + 63) / 64, 256, 0, stream>>>(
            zbuf, Mf1, y1 + (size_t)v0 * NOUT, rows);
    }
    relu_mid<<<(NV * 32 + 255) / 256, 256, 0, stream>>>(y1, b1);
    // layer 2
    for (int v0 = 0; v0 < NV; v0 += chunk2) {
        int v1 = v0 + chunk2; if (v1 > NV) v1 = NV;
        int rows = v1 - v0;
        zbuild4<OC><<<((size_t)rows * OC * 2 + 255) / 256, 256, 0, stream>>>(
            y1, SRC, REC, cursor, zbuf, v0, v1);
        gemm_mfma<K2><<<(rows + 63) / 64, 256, 0, stream>>>(
            zbuf, Mf2, y2 + (size_t)v0 * NOUT, rows);
    }
    final_k<<<(NV * 32 + 255) / 256, 256, 0, stream>>>(y2, x, Wl, bl, b2, out);
}

// Round 7
// 265.094 us; speedup vs baseline: 1.0656x; 1.0656x over previous
//
#include <hip/hip_runtime.h>
#include <hip/hip_bf16.h>
#include <cstdint>

// ---------------------------------------------------------------------------
// GemResNetBlock: two gauge-equivariant convs + Fourier ReLU + linear residual
// Round-18c: rounds 18/18b died with "container failed twice" (4 attempts) --
// suspected workspace overflow: the 18-layout grew fixed ws to ~51.7MB (XB1 +
// Y1B added) vs ~36.7MB max that ever passed, and only the Z tail is bounds-
// checked.  Fix: liveness overlays, NO behavioral change:
//  * XB1 (live: x_pack .. end of layer-1 zbuilds) ALIASES Y1B (first write:
//    relu_mid, after layer 1) -> disjoint lifetimes
//  * y2 (live: layer-2 gemm .. final_k) ALIASES y1 (last read: relu_mid)
// -> fixed layout ~33.8MB < 36.7MB known-good; Z tail gets MORE room.
// Kernel content identical to round-18:
//  * stride-1 edge walk, h-split q-half accumulators (round-17's absmax-51 bug
//    was stride-2 edge advancement under the q-split; fixed)
//  * x / y1 packed bf16 rows (16B uint4) -> one dwordx4 per gather
//  * deep pipeline: SRC 3 edges ahead, x 2 ahead, REC 1 ahead
//  * scatter_pack fused (CSR scatter + sincos + 48B REC write)
//  * LDS-staged line-coherent Z store; MFMA gemm with async B staging
#define NV     20000
#define NE     160000
#define IC1    16
#define OC     32
#define DIN    5
#define NSLOT  49
#define NOUT   160              // (o,i) = 32*5
// ---------------------------------------------------------------------------
struct SlotTables {
    int n;
    int b[64], f[64], i[64], j[64];
    float v[64];
};

constexpr SlotTables make_slots() {
    SlotTables T{};
    float K[19][5][5][5] = {};   // [basis][freq][row i][col j]
    int nb = 0;
    const int BL = 2;
    auto add = [&](int f, const float (*cb)[2], const float (*sb)[2],
                   int m, int n) {
        if (f > BL) return;
        int r0 = (m == 0) ? 0 : (2 * m - 1), nr = (m == 0) ? 1 : 2;
        int c0 = (n == 0) ? 0 : (2 * n - 1), nc = (n == 0) ? 1 : 2;
        for (int a = 0; a < nr; a++)
            for (int bb = 0; bb < nc; bb++) {
                if (f == 0) {
                    K[nb][0][r0 + a][c0 + bb] = cb[a][bb];
                } else {
                    K[nb][2 * f - 1][r0 + a][c0 + bb] = cb[a][bb];
                    K[nb][2 * f    ][r0 + a][c0 + bb] = sb[a][bb];
                }
            }
        nb++;
    };
    const float ONE[2][2]  = {{1, 0}, {0, 0}};
    const float I2[2][2]   = {{1, 0}, {0, 1}};
    const float E2[2][2]   = {{0, -1}, {1, 0}};
    const float S2[2][2]   = {{1, 0}, {0, -1}};
    const float ES2[2][2]  = {{0, 1}, {1, 0}};
    const float NS2[2][2]  = {{-1, 0}, {0, 1}};
    const float C10[2][2]  = {{1, 0}, {0, 0}};
    const float C01[2][2]  = {{0, 0}, {1, 0}};
    const float CM10[2][2] = {{-1, 0}, {0, 0}};
    const float R10[2][2]  = {{1, 0}, {0, 0}};
    const float R01[2][2]  = {{0, 1}, {0, 0}};
    const float RM10[2][2] = {{-1, 0}, {0, 0}};

    for (int m = 0; m <= 2; m++)
        for (int n = 0; n <= 2; n++) {
            if (m == 0 && n == 0) {
                add(0, ONE, ONE, 0, 0);
            } else if (n == 0) {
                add(m, C10, C01, m, 0);
                add(m, C01, CM10, m, 0);
            } else if (m == 0) {
                add(n, R10, R01, 0, n);
                add(n, R01, RM10, 0, n);
            } else {
                int d = m - n;
                int f = d >= 0 ? d : -d;
                float sg = d >= 0 ? 1.f : -1.f;
                const float sgE[2][2]  = {{0, -sg}, {sg, 0}};
                const float msgI[2][2] = {{-sg, 0}, {0, -sg}};
                add(f, I2, sgE, m, n);
                add(f, E2, msgI, m, n);
                add(m + n, S2, ES2, m, n);
                add(m + n, ES2, NS2, m, n);
            }
        }
    T.n = 0;
    for (int i = 0; i < 5; i++)
        for (int b = 0; b < nb; b++)
            for (int f = 0; f < 5; f++)
                for (int j = 0; j < 5; j++)
                    if (K[b][f][i][j] != 0.0f) {
                        T.b[T.n] = b; T.f[T.n] = f; T.i[T.n] = i;
                        T.j[T.n] = j; T.v[T.n] = K[b][f][i][j];
                        T.n++;
                    }
    return T;
}

constexpr SlotTables SL = make_slots();
static_assert(SL.n == NSLOT, "expect 49 kernel-basis nonzeros");

__device__ __forceinline__ uint32_t bf16_rne(float f) {
    uint32_t u = __float_as_uint(f);
    u += 0x7fffu + ((u >> 16) & 1u);
    return u >> 16;
}

typedef __attribute__((ext_vector_type(8))) short bf16x8;   // MFMA A/B frag
typedef __attribute__((ext_vector_type(4))) float f32x4;    // MFMA C/D frag

// ---------------- M build: M[k][n], k=(c*50+j*10+q), n=(o*5+i) -------------
template<int C>
__global__ __launch_bounds__(256) void build_M(const float* __restrict__ W,
                                               float* __restrict__ M) {
    int t = blockIdx.x * 256 + threadIdx.x;
    const int K = C * 50;
    if (t >= K * NOUT) return;
    int n = t % NOUT, k = t / NOUT;
    int o = n / 5, i = n % 5;
    int c = k / 50, r50 = k % 50;
    int j = r50 / 10, q = r50 % 10;
    int f = q >> 1, r = q & 1;
    float acc = 0.f;
    #pragma unroll
    for (int s = 0; s < NSLOT; s++) {
        if (SL.j[s] == j && SL.f[s] == f && SL.i[s] == i)
            acc += SL.v[s] * W[(size_t)((SL.b[s] * 2 + r) * 32 + o) * C + c];
    }
    M[(size_t)k * NOUT + n] = acc;
}

// Swizzle M into MFMA B-fragment order (bf16):
// Mf[((ck*10+nt)*64+lane)*4+a] packs B[k0][col],B[k0+1][col]
// with k0 = ck*32 + (lane>>4)*8 + 2a, col = nt*16 + (lane&15).
template<int K>
__global__ __launch_bounds__(256) void build_Mfrag(const float* __restrict__ M,
                                                   uint32_t* __restrict__ Mf) {
    int t = blockIdx.x * 256 + threadIdx.x;
    const int total = (K / 32) * 10 * 64 * 4;
    if (t >= total) return;
    int a = t & 3;
    int idx = t >> 2;
    int lane = idx & 63; idx >>= 6;
    int nt = idx % 10;
    int ck = idx / 10;
    int col = nt * 16 + (lane & 15);
    int k0 = ck * 32 + (lane >> 4) * 8 + 2 * a;
    uint32_t lo = bf16_rne(M[(size_t)k0 * NOUT + col]);
    uint32_t hi = bf16_rne(M[(size_t)(k0 + 1) * NOUT + col]);
    Mf[t] = lo | (hi << 16);
}

// ---------------- CSR build ------------------------------------------------
__global__ __launch_bounds__(256) void hist_k(const int* __restrict__ ei,
                                              int* __restrict__ counts) {
    int e = blockIdx.x * 256 + threadIdx.x;
    if (e < NE) atomicAdd(&counts[ei[e]], 1);   // ei[e] = dst
}

__global__ __launch_bounds__(1024) void scan_k(const int* __restrict__ counts,
                                               int* __restrict__ cursor) {
    __shared__ int part[1024];
    int t = threadIdx.x;
    int base = t * 20;
    int local[20];
    int s = 0;
    #pragma unroll
    for (int k = 0; k < 20; k++) {
        int idx = base + k;
        int c = (idx < NV) ? counts[idx] : 0;
        local[k] = c; s += c;
    }
    part[t] = s;
    __syncthreads();
    for (int off = 1; off < 1024; off <<= 1) {
        int add = (t >= off) ? part[t - off] : 0;
        __syncthreads();
        part[t] += add;
        __syncthreads();
    }
    int run = (t == 0) ? 0 : part[t - 1];
    #pragma unroll
    for (int k = 0; k < 20; k++) {
        int idx = base + k;
        if (idx < NV) { cursor[idx] = run; run += local[k]; }
    }
}

// Fused scatter + edge-record pack: for each edge e (sequential reads of
// ei/pre/conn), claim CSR slot pos, write SRC[pos] and REC[pos] directly.
// Slot NE = zero record (pipeline clamp).  Edge order within a vertex is
// atomic-nondeterministic; the sum is order-independent.
__global__ __launch_bounds__(256) void scatter_pack(const int* __restrict__ ei,
                                                    const float* __restrict__ pre,
                                                    const float* __restrict__ conn,
                                                    int* __restrict__ cursor,
                                                    int* __restrict__ SRC,
                                                    float4* __restrict__ REC) {
    int e = blockIdx.x * 256 + threadIdx.x;
    if (e == 0) {
        SRC[NE] = 0;
        REC[(size_t)NE * 3 + 0] = float4{0.f, 0.f, 0.f, 0.f};
        REC[(size_t)NE * 3 + 1] = float4{0.f, 0.f, 0.f, 0.f};
        REC[(size_t)NE * 3 + 2] = float4{0.f, 0.f, 0.f, 0.f};
    }
    if (e >= NE) return;
    int pos = atomicAdd(&cursor[ei[e]], 1);
    SRC[pos] = ei[NE + e];
    float al = conn[e];
    float c1 = __cosf(al), s1 = __sinf(al);
    const float* pp = pre + (size_t)e * 10;
    REC[(size_t)pos * 3 + 0] = float4{c1, s1, pp[0], pp[1]};
    REC[(size_t)pos * 3 + 1] = float4{pp[2], pp[3], pp[4], pp[5]};
    REC[(size_t)pos * 3 + 2] = float4{pp[6], pp[7], pp[8], pp[9]};
}

// ---------------- bf16 row packing (gather-footprint halving) --------------
// Row (v,c) = 5 values -> uint4 {x0x1, x2x3, x4--, 0}; one dwordx4 per gather.
__global__ __launch_bounds__(256) void x_pack(const float* __restrict__ x,
                                              uint4* __restrict__ xb) {
    int t = blockIdx.x * 256 + threadIdx.x;
    if (t >= NV * IC1) return;
    const float* xr = x + (size_t)t * 5;
    uint4 o;
    o.x = bf16_rne(xr[0]) | (bf16_rne(xr[1]) << 16);
    o.y = bf16_rne(xr[2]) | (bf16_rne(xr[3]) << 16);
    o.z = bf16_rne(xr[4]);
    o.w = 0;
    xb[t] = o;
}

// ---------------- Z build v6: h-split (q-halves) + packed-x + prefetch -----
// Thread t: pair = t>>1 = (v-v0)*C + c, h = t&1.  BOTH threads of a pair walk
// ALL edges stride-1; lane h accumulates only q-half {5h..5h+4} (25 regs).
// Pipeline: SRC 3 edges ahead, x (packed uint4) 2 ahead, REC 1 ahead; clamp
// index NE -> zero record (never folded in: break precedes the swap).
// All register-array indices compile-time constant.
template<int C>
__global__ __launch_bounds__(256) void zbuild6(const uint4* __restrict__ xb,
                                               const int*   __restrict__ SRC,
                                               const float4* __restrict__ REC,
                                               const int* __restrict__ cursor,
                                               uint32_t* __restrict__ Z,
                                               int v0, int v1) {
    __shared__ uint32_t st[3200];        // 128 pairs x 25 uints = 12.8 KB
    int tid = threadIdx.x;
    int t = blockIdx.x * 256 + tid;
    int pair = t >> 1, h = t & 1;
    int npairs = (v1 - v0) * C;
    bool valid = pair < npairs;
    int c = pair % C;
    int v = v0 + (valid ? pair / C : 0);
    int beg = 0, end = 0;
    if (valid) { beg = (v == 0) ? 0 : cursor[v - 1]; end = cursor[v]; }

    float acc[25];
    #pragma unroll
    for (int z = 0; z < 25; z++) acc[z] = 0.f;

    int k = beg;
    if (k < end) {
        int k1 = (k + 1 < end) ? k + 1 : NE;
        int k2 = (k + 2 < end) ? k + 2 : NE;
        int s0 = SRC[k], s1i = SRC[k1], s2i = SRC[k2];
        const float4* rp = REC + (size_t)k * 3;
        float4 r0 = rp[0], r1 = rp[1], r2 = rp[2];
        uint4 u0 = xb[(size_t)s0 * C + c];
        uint4 u1 = xb[(size_t)s1i * C + c];
        while (true) {
            bool more = (k1 != NE);
            int k3 = (k + 3 < end) ? k + 3 : NE;
            int s3i = SRC[k3];                          // SRC 3 ahead
            uint4 u2 = xb[(size_t)s2i * C + c];         // x 2 ahead
            const float4* rpn = REC + (size_t)k1 * 3;   // REC 1 ahead
            float4 n0 = rpn[0], n1 = rpn[1], n2 = rpn[2];
            // unpack current x (bf16<<16 is the f32 bit pattern)
            float x0 = __uint_as_float(u0.x << 16);
            float x1 = __uint_as_float(u0.x & 0xffff0000u);
            float x2 = __uint_as_float(u0.y << 16);
            float x3 = __uint_as_float(u0.y & 0xffff0000u);
            float x4 = __uint_as_float(u0.z << 16);
            // compute current edge
            float cc1 = r0.x, ss1 = r0.y;
            float cc2 = cc1 * cc1 - ss1 * ss1, ss2 = 2.f * cc1 * ss1;
            float xt[5];
            xt[0] = x0;
            xt[1] = cc1 * x1 - ss1 * x2;
            xt[2] = ss1 * x1 + cc1 * x2;
            xt[3] = cc2 * x3 - ss2 * x4;
            xt[4] = ss2 * x3 + cc2 * x4;
            // q-half select, constant component indices only
            float ph[5];
            ph[0] = h ? r1.w : r0.z;    // p5 : p0
            ph[1] = h ? r2.x : r0.w;    // p6 : p1
            ph[2] = h ? r2.y : r1.x;    // p7 : p2
            ph[3] = h ? r2.z : r1.y;    // p8 : p3
            ph[4] = h ? r2.w : r1.z;    // p9 : p4
            #pragma unroll
            for (int j = 0; j < 5; j++)
                #pragma unroll
                for (int w = 0; w < 5; w++)
                    acc[j * 5 + w] = fmaf(xt[j], ph[w], acc[j * 5 + w]);
            if (!more) break;
            k = k1; k1 = k2; k2 = k3;
            r0 = n0; r1 = n1; r2 = n2;
            u0 = u1; u1 = u2;
            s2i = s3i;
        }
    }
    // assemble the 25-uint packed row for this pair.
    //   w=0,1 -> q0..3 (h=0 local); w=2 -> q4 (h=0) + q5 (h=1, shfl);
    //   w=3,4 -> q6..9 (h=1 local)
    uint32_t* sb = st + (tid >> 1) * 25;
    #pragma unroll
    for (int j = 0; j < 5; j++) {
        float q5v = __shfl_xor(acc[j * 5 + 0], 1);   // h=1's p5-acc -> h=0
        if (h == 0) {
            sb[j * 5 + 0] = bf16_rne(acc[j * 5 + 0]) | (bf16_rne(acc[j * 5 + 1]) << 16);
            sb[j * 5 + 1] = bf16_rne(acc[j * 5 + 2]) | (bf16_rne(acc[j * 5 + 3]) << 16);
            sb[j * 5 + 2] = bf16_rne(acc[j * 5 + 4]) | (bf16_rne(q5v) << 16);
        } else {
            sb[j * 5 + 3] = bf16_rne(acc[j * 5 + 1]) | (bf16_rne(acc[j * 5 + 2]) << 16);
            sb[j * 5 + 4] = bf16_rne(acc[j * 5 + 3]) | (bf16_rne(acc[j * 5 + 4]) << 16);
        }
    }
    __syncthreads();
    // linear block writeout: each store inst covers contiguous cache lines
    size_t gbase = (size_t)blockIdx.x * 3200;
    int pbase = blockIdx.x * 128;
    for (int i = tid; i < 3200; i += 256)
        if (pbase + i / 25 < npairs) Z[gbase + i] = st[i];
}

// ---------------- MFMA GEMM: Y[v,n] = sum_k Z[v,k]*M[k,n] ------------------
// 4 waves/block, 64 rows/block, all 160 cols.  B-frags (identical for the 4
// waves) live in double-buffered LDS, filled by async DMA (global_load_lds,
// width 16): per chunk, stage chunk ck+1 into Bs[buf^1] BEFORE computing ck,
// prefetch A one chunk ahead in regs, one __syncthreads per chunk.
template<int K>
__global__ __launch_bounds__(256) void gemm_mfma(const uint32_t* __restrict__ Z,
                                                 const uint32_t* __restrict__ Mf,
                                                 float* __restrict__ Y,
                                                 int rows) {
    constexpr int NC = K / 32;
    __shared__ uint4 Bs[2][640];        // 2 x 10 KB
    int t = threadIdx.x;
    int lane = t & 63;
    int wave = t >> 6;
    int r0 = blockIdx.x * 64 + wave * 16;
    int mrow = lane & 15;
    int q = lane >> 4;
    int ra = r0 + mrow;
    if (ra >= rows) ra = rows - 1;          // clamp A loads; store masked
    const uint32_t* za = Z + (size_t)ra * (K / 2) + q * 4;
    const uint4* mfg = (const uint4*)Mf + lane;

    auto stage = [&](int ck, int nb) {
        const uint4* gp = mfg + (size_t)ck * 640;
        for (int i = wave; i < 10; i += 4)
            __builtin_amdgcn_global_load_lds(
                (const __attribute__((address_space(1))) void*)(gp + i * 64),
                (__attribute__((address_space(3))) void*)(&Bs[nb][i * 64]),
                16, 0, 0);
    };

    f32x4 acc[10];
    #pragma unroll
    for (int nt = 0; nt < 10; nt++) acc[nt] = {0.f, 0.f, 0.f, 0.f};

    stage(0, 0);
    bf16x8 af = *(const bf16x8*)za;         // A chunk 0 (overlaps DMA wait)
    __syncthreads();

    for (int ck = 0; ck < NC; ck++) {
        int buf = ck & 1;
        bf16x8 af_n = af;
        if (ck + 1 < NC) {
            stage(ck + 1, buf ^ 1);         // async DMA, consumed next iter
            af_n = *(const bf16x8*)(za + (ck + 1) * 16);
        }
        bf16x8 bf[10];
        #pragma unroll
        for (int nt = 0; nt < 10; nt++)
            bf[nt] = *(const bf16x8*)&Bs[buf][nt * 64 + lane];
        #pragma unroll
        for (int nt = 0; nt < 10; nt++)
            acc[nt] = __builtin_amdgcn_mfma_f32_16x16x32_bf16(af, bf[nt],
                                                              acc[nt], 0, 0, 0);
        af = af_n;
        __syncthreads();                    // drain DMA + protect Bs[buf]
    }
    // C/D layout: col = lane&15, row = q*4 + reg  [verified m89/m91]
    #pragma unroll
    for (int reg = 0; reg < 4; reg++) {
        int rr = r0 + q * 4 + reg;
        if (rr < rows) {
            float* yb = Y + (size_t)rr * NOUT + (lane & 15);
            #pragma unroll
            for (int nt = 0; nt < 10; nt++) yb[nt * 16] = acc[nt][reg];
        }
    }
}

// ---------------- Fourier ReLU + epilogues ---------------------------------
__device__ __forceinline__ void fourier_relu(float d0, float d1, float d2,
                                             float d3, float d4, float* out5) {
    float o0 = 0, o1 = 0, o2 = 0, o3 = 0, o4 = 0;
    #pragma unroll
    for (int k = 0; k < 7; k++) {
        float th = (float)k * (6.28318530717958647692f / 7.0f);
        float ck = __cosf(th), sk = __sinf(th);
        float c2k = ck * ck - sk * sk, s2k = 2.f * ck * sk;
        float sv = d0 + ck * d1 + sk * d2 + c2k * d3 + s2k * d4;
        sv = fmaxf(sv, 0.f);
        o0 += sv; o1 += sv * ck; o2 += sv * sk; o3 += sv * c2k; o4 += sv * s2k;
    }
    const float i7 = 1.0f / 7.0f;
    out5[0] = o0 * i7; out5[1] = o1 * (2.f * i7); out5[2] = o2 * (2.f * i7);
    out5[3] = o3 * (2.f * i7); out5[4] = o4 * (2.f * i7);
}

// relu_mid also emits the packed-bf16 y1 rows consumed by zbuild6<OC>.
__global__ __launch_bounds__(256) void relu_mid(const float* __restrict__ y,
                                                const float* __restrict__ b1,
                                                uint4* __restrict__ yb) {
    int t = blockIdx.x * 256 + threadIdx.x;     // v*32 + ch
    if (t >= NV * 32) return;
    int ch = t & 31;
    const float* yr = y + (size_t)t * 5;
    float r[5];
    fourier_relu(yr[0] + b1[ch], yr[1], yr[2], yr[3], yr[4], r);
    uint4 o;
    o.x = bf16_rne(r[0]) | (bf16_rne(r[1]) << 16);
    o.y = bf16_rne(r[2]) | (bf16_rne(r[3]) << 16);
    o.z = bf16_rne(r[4]);
    o.w = 0;
    yb[t] = o;
}

__global__ __launch_bounds__(256) void final_k(const float* __restrict__ y2,
                                               const float* __restrict__ x,
                                               const float* __restrict__ Wl,
                                               const float* __restrict__ bl,
                                               const float* __restrict__ b2,
                                               float* __restrict__ out) {
    int t = blockIdx.x * 256 + threadIdx.x;     // v*32 + o
    if (t >= NV * 32) return;
    int o = t & 31;
    int v = t >> 5;
    float r0 = 0, r1 = 0, r2 = 0, r3 = 0, r4 = 0;
    const float* xb = x + (size_t)v * (IC1 * DIN);
    const float* wl = Wl + o * IC1;
    #pragma unroll
    for (int c = 0; c < IC1; c++) {
        float w = wl[c];
        r0 = fmaf(w, xb[c*5+0], r0); r1 = fmaf(w, xb[c*5+1], r1);
        r2 = fmaf(w, xb[c*5+2], r2); r3 = fmaf(w, xb[c*5+3], r3);
        r4 = fmaf(w, xb[c*5+4], r4);
    }
    float blo = bl[o];
    const float* yb = y2 + (size_t)t * 5;
    float d0 = yb[0] + b2[o] + r0 + blo;
    float d1 = yb[1] + r1 + blo;
    float d2 = yb[2] + r2 + blo;
    float d3 = yb[3] + r3 + blo;
    float d4 = yb[4] + r4 + blo;
    float r[5];
    fourier_relu(d0, d1, d2, d3, d4, r);
    float* ob = out + (size_t)t * 5;
    #pragma unroll
    for (int d = 0; d < 5; d++) ob[d] = r[d];
}

extern "C" void kernel_launch(void* const* d_in, const int* in_sizes, int n_in,
                              void* d_out, int out_size, void* d_ws, size_t ws_size,
                              hipStream_t stream) {
    const float* x    = (const float*)d_in[0];
    const int*   ei   = (const int*)  d_in[1];
    const float* pre  = (const float*)d_in[2];
    const float* conn = (const float*)d_in[3];
    const float* W1   = (const float*)d_in[4];
    const float* b1   = (const float*)d_in[5];
    const float* W2   = (const float*)d_in[6];
    const float* b2   = (const float*)d_in[7];
    const float* Wl   = (const float*)d_in[8];
    const float* bl   = (const float*)d_in[9];
    float* out = (float*)d_out;

    const int K1 = IC1 * 50;   // 800
    const int K2 = OC  * 50;   // 1600

    // ws layout (overlayed, ~33.8MB fixed):
    //   y1 (12.8MB, ALSO y2: y1 last read by relu_mid, y2 first write after)
    //   M1 | M2 | Mf1 | Mf2 | csr | REC | SRC
    //   Y1B (10.24MB, ALSO XB1: XB1 dead before relu_mid writes Y1B)
    //   Ztail
    const size_t Y_BYTES   = (size_t)NV * NOUT * sizeof(float);     // 12.8 MB
    const size_t M1_BYTES  = (size_t)K1 * NOUT * sizeof(float);     // 512 KB
    const size_t M2_BYTES  = (size_t)K2 * NOUT * sizeof(float);     // 1 MB
    const size_t MF1_BYTES = (size_t)(K1 / 32) * 10 * 64 * 16;      // 256 KB
    const size_t MF2_BYTES = (size_t)(K2 / 32) * 10 * 64 * 16;      // 512 KB
    const size_t CSR_BYTES = (size_t)(2 * NV) * sizeof(int);        // 160 KB
    const size_t REC_BYTES = (size_t)(NE + 1) * 48;                 // 7.68 MB
    const size_t SRC_BYTES = (((size_t)(NE + 1) * 4 + 15) / 16) * 16;
    const size_t Y1B_BYTES = (size_t)NV * OC * 16;                  // 10.24 MB
    char* ws = (char*)d_ws;
    float* y1 = (float*)(ws);
    float* y2 = y1;                               // overlay (disjoint lifetimes)
    float* M1 = (float*)(ws + Y_BYTES);
    float* M2 = (float*)(ws + Y_BYTES + M1_BYTES);
    uint32_t* Mf1 = (uint32_t*)(ws + Y_BYTES + M1_BYTES + M2_BYTES);
    uint32_t* Mf2 = (uint32_t*)(ws + Y_BYTES + M1_BYTES + M2_BYTES + MF1_BYTES);
    int* counts = (int*)(ws + Y_BYTES + M1_BYTES + M2_BYTES + MF1_BYTES + MF2_BYTES);
    int* cursor = counts + NV;
    size_t csr_end = Y_BYTES + M1_BYTES + M2_BYTES + MF1_BYTES + MF2_BYTES
                   + CSR_BYTES;
    float4* REC = (float4*)(ws + csr_end);
    int*    SRC = (int*)(ws + csr_end + REC_BYTES);
    uint4*  Y1B = (uint4*)(ws + csr_end + REC_BYTES + SRC_BYTES);
    uint4*  XB1 = Y1B;                            // overlay (disjoint lifetimes)
    size_t fixed = csr_end + REC_BYTES + SRC_BYTES + Y1B_BYTES;

    // Z buffer (bf16): ws tail if it has room, else d_out (dead until final_k)
    size_t tail = (ws_size > fixed) ? (ws_size - fixed) : 0;
    uint32_t* zbuf;
    size_t zcap;
    if (tail >= Y_BYTES) { zbuf = (uint32_t*)(ws + fixed); zcap = tail; }
    else                 { zbuf = (uint32_t*)d_out;        zcap = Y_BYTES; }
    int chunk1 = (int)(zcap / ((size_t)K1 * 2)); if (chunk1 > NV) chunk1 = NV;
    int chunk2 = (int)(zcap / ((size_t)K2 * 2)); if (chunk2 > NV) chunk2 = NV;

    hipMemsetAsync(counts, 0, NV * sizeof(int), stream);

    build_M<IC1><<<(K1 * NOUT + 255) / 256, 256, 0, stream>>>(W1, M1);
    build_M<OC> <<<(K2 * NOUT + 255) / 256, 256, 0, stream>>>(W2, M2);
    build_Mfrag<K1><<<((K1 / 32) * 2560 + 255) / 256, 256, 0, stream>>>(M1, Mf1);
    build_Mfrag<K2><<<((K2 / 32) * 2560 + 255) / 256, 256, 0, stream>>>(M2, Mf2);

    hist_k<<<(NE + 255) / 256, 256, 0, stream>>>(ei, counts);
    scan_k<<<1, 1024, 0, stream>>>(counts, cursor);
    scatter_pack<<<(NE + 255) / 256, 256, 0, stream>>>(ei, pre, conn, cursor,
                                                       SRC, REC);
    x_pack<<<(NV * IC1 + 255) / 256, 256, 0, stream>>>(x, XB1);

    // layer 1
    for (int v0 = 0; v0 < NV; v0 += chunk1) {
        int v1 = v0 + chunk1; if (v1 > NV) v1 = NV;
        int rows = v1 - v0;
        zbuild6<IC1><<<((size_t)rows * IC1 * 2 + 255) / 256, 256, 0, stream>>>(
            XB1, SRC, REC, cursor, zbuf, v0, v1);
        gemm_mfma<K1><<<(rows + 63) / 64, 256, 0, stream>>>(
            zbuf, Mf1, y1 + (size_t)v0 * NOUT, rows);
    }
    relu_mid<<<(NV * 32 + 255) / 256, 256, 0, stream>>>(y1, b1, Y1B);
    // layer 2
    for (int v0 = 0; v0 < NV; v0 += chunk2) {
        int v1 = v0 + chunk2; if (v1 > NV) v1 = NV;
        int rows = v1 - v0;
        zbuild6<OC><<<((size_t)rows * OC * 2 + 255) / 256, 256, 0, stream>>>(
            Y1B, SRC, REC, cursor, zbuf, v0, v1);
        gemm_mfma<K2><<<(rows + 63) / 64, 256, 0, stream>>>(
            zbuf, Mf2, y2 + (size_t)v0 * NOUT, rows);
    }
    final_k<<<(NV * 32 + 255) / 256, 256, 0, stream>>>(y2, x, Wl, bl, b2, out);
}